// Round 4
// baseline (237.489 us; speedup 1.0000x reference)
//
#include <hip/hip_runtime.h>

#define BATCH 256
#define SEQ   256
#define CDIM  384
#define HDIM  64

typedef __attribute__((ext_vector_type(8))) short bf16x8;
typedef __attribute__((ext_vector_type(4))) float f32x4;

__device__ __forceinline__ unsigned f2bf(float f) {
  union { float f; unsigned u; } v; v.f = f;
  unsigned r = v.u + 0x7FFFu + ((v.u >> 16) & 1u);   // RNE
  return r >> 16;
}

// ---------------------------------------------------------------------------
// kernel 0: WT[n][kk] = W*[kk][n] as bf16.  n: 0-63 -> Wq, 64-127 -> Wk,
// 128-191 -> Wv.  Tiny; L2-resident.
// ---------------------------------------------------------------------------
__global__ void wtrans_kernel(const float* __restrict__ Wk, const float* __restrict__ Wq,
                              const float* __restrict__ Wv, unsigned short* __restrict__ WT) {
  int gid = blockIdx.x * 256 + threadIdx.x;
  if (gid >= 192 * CDIM) return;
  int n = gid / CDIM, kk = gid - n * CDIM;
  const float* W = (n < 64) ? Wq : (n < 128) ? Wk : Wv;
  WT[gid] = (unsigned short)f2bf(W[kk * HDIM + (n & 63)]);
}

// ---------------------------------------------------------------------------
// kernel 1: q,k,v = x @ [Wq|Wk|Wv].  1024 blocks x 256 thr, wave = 16 t-rows.
// nt-OUTER structure: x loaded+packed ONCE into bx[12] (48 VGPRs, live all
// kernel); per nt: 12 WT b-frag loads, then an inline-asm scheduling fence
// (memory clobber = region boundary: loads can't sink, MFMAs can't hoist),
// then 12 MFMAs -> waitcnt pass emits progressive vmcnt(11..0) drain instead
// of 14 serialized full stalls.  amdgpu_waves_per_eu(4,4) stops the
// register allocator from chasing 8 waves/EU (round-3 failure: VGPR=40).
// ---------------------------------------------------------------------------
__global__ __launch_bounds__(256, 4) __attribute__((amdgpu_waves_per_eu(4, 4)))
void proj_kernel(
    const float* __restrict__ x, const unsigned short* __restrict__ WT,
    unsigned short* __restrict__ qws, unsigned short* __restrict__ kws,
    unsigned short* __restrict__ vT) {
  __shared__ unsigned short vtile[64][72];   // 9216 B
  const int tid = threadIdx.x, bid = blockIdx.x;
  const int w = tid >> 6, lane = tid & 63;
  const int ln15 = lane & 15, quad = lane >> 4;
  const int t0 = bid * 64 + w * 16;

  const float* xrow = x + (size_t)(t0 + ln15) * CDIM + quad * 8;
  const unsigned short* wbase = WT + (size_t)ln15 * CDIM + quad * 8;

  // Phase 1: load + pack all x for this wave's 16 rows (2 fenced batches of 12)
  bf16x8 bx[12];
  #pragma unroll
  for (int hh = 0; hh < 2; ++hh) {
    float4 A[12];
    #pragma unroll
    for (int j = 0; j < 6; ++j) {
      A[2 * j]     = *(const float4*)(xrow + (hh * 6 + j) * 32);
      A[2 * j + 1] = *(const float4*)(xrow + (hh * 6 + j) * 32 + 4);
    }
    asm volatile("" ::: "memory");           // batch the 12 loads
    #pragma unroll
    for (int j = 0; j < 6; ++j) {
      bf16x8 t;
      t[0] = (short)f2bf(A[2 * j].x);     t[1] = (short)f2bf(A[2 * j].y);
      t[2] = (short)f2bf(A[2 * j].z);     t[3] = (short)f2bf(A[2 * j].w);
      t[4] = (short)f2bf(A[2 * j + 1].x); t[5] = (short)f2bf(A[2 * j + 1].y);
      t[6] = (short)f2bf(A[2 * j + 1].z); t[7] = (short)f2bf(A[2 * j + 1].w);
      bx[hh * 6 + j] = t;
    }
  }

  // Phase 2: per h-tile, fenced 12-load batch then 12-MFMA chain
  #pragma unroll
  for (int nt = 0; nt < 12; ++nt) {
    bf16x8 aw[12];
    #pragma unroll
    for (int ks = 0; ks < 12; ++ks)
      aw[ks] = *(const bf16x8*)(wbase + (size_t)nt * 16 * CDIM + ks * 32);
    asm volatile("" ::: "memory");           // 12 loads in flight -> one drain
    f32x4 a = (f32x4){0.f, 0.f, 0.f, 0.f};
    #pragma unroll
    for (int ks = 0; ks < 12; ++ks)
      a = __builtin_amdgcn_mfma_f32_16x16x32_bf16(aw[ks], bx[ks], a, 0, 0, 0);

    // epilogue: lane owns qkv[t0+ln15][nt*16 + quad*4 .. +3]
    unsigned p0 = f2bf(a[0]) | (f2bf(a[1]) << 16);
    unsigned p1 = f2bf(a[2]) | (f2bf(a[3]) << 16);
    int hl = (nt & 3) * 16 + quad * 4;
    if (nt < 8) {
      unsigned short* dst = (nt < 4) ? qws : kws;
      *(uint2*)&dst[(size_t)(t0 + ln15) * HDIM + hl] = (uint2){p0, p1};
    } else {
      int tl = w * 16 + ln15;                // block-local t (0..63)
      vtile[hl + 0][tl] = (unsigned short)(p0 & 0xFFFF);
      vtile[hl + 1][tl] = (unsigned short)(p0 >> 16);
      vtile[hl + 2][tl] = (unsigned short)(p1 & 0xFFFF);
      vtile[hl + 3][tl] = (unsigned short)(p1 >> 16);
    }
  }
  __syncthreads();
  {
    int h = tid >> 2, c = tid & 3;
    uint4 d0 = *(const uint4*)&vtile[h][c * 16];
    uint4 d1 = *(const uint4*)&vtile[h][c * 16 + 8];
    unsigned short* dst = &vT[((size_t)(bid >> 2) * 64 + h) * SEQ + (bid & 3) * 64 + c * 16];
    *(uint4*)dst = d0;
    *(uint4*)(dst + 8) = d1;
  }
}

// ---------------------------------------------------------------------------
// kernel 2: causal attention.  512 blocks x 512 thr: block (2b+h) does half of
// batch b's 16 m-tiles; cost-balanced groups A={0,3,4,7,8,11,12,15},
// B={1,2,5,6,9,10,13,14} (72 cost units each; mt = 4*(w>>1) + (h? 1+(w&1)
// : 3*(w&1))).  One mt per wave.  LDS 79,872 B <= 81,920 -> 2 blocks/CU =
// 16 waves/CU (round-3 failure: grid 256 left each CU at 8 waves).
// k/vT staged via coalesced uint4; PV through per-wave 16x32 P buffer
// (wave-private, no barriers after staging sync).
// ---------------------------------------------------------------------------
__global__ __launch_bounds__(512, 4) __attribute__((amdgpu_waves_per_eu(4, 4)))
void attn_kernel(
    const unsigned short* __restrict__ qws, const unsigned short* __restrict__ kws,
    const unsigned short* __restrict__ vT, float* __restrict__ out) {
  __shared__ unsigned short kl[256][72];     // 36864 B
  __shared__ unsigned short vt[64][264];     // 33792 B
  __shared__ unsigned short pl[8][16][36];   // 9216 B   (total 79872 B)
  const int tid = threadIdx.x;
  const int b = blockIdx.x >> 1, hgrp = blockIdx.x & 1;
  const int w = tid >> 6, lane = tid & 63;
  const int ln15 = lane & 15, quad = lane >> 4;

  for (int c = tid; c < 2048; c += 512) {    // k: 256x64 bf16
    int t = c >> 3, hc = c & 7;
    *(uint4*)&kl[t][hc * 8] = *(const uint4*)&kws[(size_t)(b * 256 + t) * HDIM + hc * 8];
  }
  for (int c = tid; c < 2048; c += 512) {    // vT[b]: 64x256 bf16, straight copy
    int hh = c >> 5, tc = c & 31;
    *(uint4*)&vt[hh][tc * 8] = *(const uint4*)&vT[(size_t)(b * 64 + hh) * SEQ + tc * 8];
  }
  __syncthreads();

  const int mt = 4 * (w >> 1) + (hgrp ? (1 + (w & 1)) : (3 * (w & 1)));
  const int t0 = mt * 16;
  const int NT = (mt | 1) + 1;               // even # of 16-wide s-tiles

  bf16x8 aq[2];
  #pragma unroll
  for (int ks = 0; ks < 2; ++ks)
    aq[ks] = *(const bf16x8*)&qws[(size_t)(b * 256 + t0 + ln15) * HDIM + ks * 32 + quad * 8];

  float sv[16][4];
  #pragma unroll
  for (int nt = 0; nt < 16; ++nt) {
    if (nt < NT) {
      f32x4 acc = (f32x4){0.f, 0.f, 0.f, 0.f};
      #pragma unroll
      for (int ks = 0; ks < 2; ++ks) {
        bf16x8 bf = *(const bf16x8*)&kl[nt * 16 + ln15][ks * 32 + quad * 8];
        acc = __builtin_amdgcn_mfma_f32_16x16x32_bf16(aq[ks], bf, acc, 0, 0, 0);
      }
      int colg = nt * 16 + ln15;
      #pragma unroll
      for (int i = 0; i < 4; ++i) {
        int rowg = t0 + quad * 4 + i;
        sv[nt][i] = (colg <= rowg) ? acc[i] * 0.125f : -3.0e38f;  // 1/sqrt(64)
      }
    }
  }
  float mx[4] = {-3.0e38f, -3.0e38f, -3.0e38f, -3.0e38f};
  #pragma unroll
  for (int nt = 0; nt < 16; ++nt)
    if (nt < NT) {
      #pragma unroll
      for (int i = 0; i < 4; ++i) mx[i] = fmaxf(mx[i], sv[nt][i]);
    }
  #pragma unroll
  for (int i = 0; i < 4; ++i) {              // reduce across the 16-lane group
    mx[i] = fmaxf(mx[i], __shfl_xor(mx[i], 8, 64));
    mx[i] = fmaxf(mx[i], __shfl_xor(mx[i], 4, 64));
    mx[i] = fmaxf(mx[i], __shfl_xor(mx[i], 2, 64));
    mx[i] = fmaxf(mx[i], __shfl_xor(mx[i], 1, 64));
  }
  float sm[4] = {0.f, 0.f, 0.f, 0.f};
  #pragma unroll
  for (int nt = 0; nt < 16; ++nt)
    if (nt < NT) {
      #pragma unroll
      for (int i = 0; i < 4; ++i) {
        float e = __expf(sv[nt][i] - mx[i]);
        sv[nt][i] = e;
        sm[i] += e;
      }
    }
  #pragma unroll
  for (int i = 0; i < 4; ++i) {
    sm[i] += __shfl_xor(sm[i], 8, 64);
    sm[i] += __shfl_xor(sm[i], 4, 64);
    sm[i] += __shfl_xor(sm[i], 2, 64);
    sm[i] += __shfl_xor(sm[i], 1, 64);
  }
  float inv[4];
  #pragma unroll
  for (int i = 0; i < 4; ++i) inv[i] = 1.0f / sm[i];

  // PV in 32-wide K chunks through the per-wave P buffer (wave-private; DS
  // pipe in-order so no barriers needed).
  f32x4 o[4];
  #pragma unroll
  for (int ont = 0; ont < 4; ++ont) o[ont] = (f32x4){0.f, 0.f, 0.f, 0.f};

  for (int kc = 0; kc < 8; ++kc) {
    if (kc * 2 < NT) {
      #pragma unroll
      for (int half = 0; half < 2; ++half) {
        int nt = kc * 2 + half;
        #pragma unroll
        for (int i = 0; i < 4; ++i)
          pl[w][quad * 4 + i][half * 16 + ln15] =
              (unsigned short)f2bf(sv[nt][i] * inv[i]);
      }
      bf16x8 pa = *(const bf16x8*)&pl[w][ln15][quad * 8];
      #pragma unroll
      for (int ont = 0; ont < 4; ++ont) {
        bf16x8 vb = *(const bf16x8*)&vt[ont * 16 + ln15][kc * 32 + quad * 8];
        o[ont] = __builtin_amdgcn_mfma_f32_16x16x32_bf16(pa, vb, o[ont], 0, 0, 0);
      }
    }
  }

  #pragma unroll
  for (int ont = 0; ont < 4; ++ont) {
    int h = ont * 16 + ln15;
    #pragma unroll
    for (int i = 0; i < 4; ++i)
      out[(size_t)(b * 256 + t0 + quad * 4 + i) * HDIM + h] = o[ont][i];
  }
}

// ---------------------------------------------------------------------------
// ws layout: WT bf16 @0 (147456 B, pad to 256 KB), then q/k bf16 row-major and
// vT bf16 [B][H][T] (8 MB each).  Needs ws_size >= 24.5 MB.
// ---------------------------------------------------------------------------
extern "C" void kernel_launch(void* const* d_in, const int* in_sizes, int n_in,
                              void* d_out, int out_size, void* d_ws, size_t ws_size,
                              hipStream_t stream) {
  const float* x  = (const float*)d_in[0];
  const float* Wk = (const float*)d_in[1];
  const float* Wq = (const float*)d_in[2];
  const float* Wv = (const float*)d_in[3];
  float* out = (float*)d_out;

  char* ws = (char*)d_ws;
  unsigned short* WT  = (unsigned short*)ws;
  unsigned short* qws = (unsigned short*)(ws + 262144);
  unsigned short* kws = qws + (size_t)BATCH * SEQ * HDIM;
  unsigned short* vT  = kws + (size_t)BATCH * SEQ * HDIM;

  wtrans_kernel<<<(192 * CDIM + 255) / 256, 256, 0, stream>>>(Wk, Wq, Wv, WT);
  proj_kernel<<<1024, 256, 0, stream>>>(x, WT, qws, kws, vT);
  attn_kernel<<<2 * BATCH, 512, 0, stream>>>(qws, kws, vT, out);
}

// Round 5
// 182.607 us; speedup vs baseline: 1.3005x; 1.3005x over previous
//
#include <hip/hip_runtime.h>

#define BATCH 256
#define SEQ   256
#define CDIM  384
#define HDIM  64

typedef __attribute__((ext_vector_type(8))) short bf16x8;
typedef __attribute__((ext_vector_type(4))) float f32x4;

__device__ __forceinline__ unsigned f2bf(float f) {
  union { float f; unsigned u; } v; v.f = f;
  unsigned r = v.u + 0x7FFFu + ((v.u >> 16) & 1u);   // RNE
  return r >> 16;
}

// ---------------------------------------------------------------------------
// kernel 0: WTf = W* transposed+bf16 in MFMA FRAGMENT ORDER:
//   frag record (ks,nt) = 64 lanes x 16 B; lane (ln15 + 16*quad) holds
//   WT row (nt*16+ln15), cols ks*32+quad*8 .. +7.
//   idx = ((ks*12 + nt)*64 + lane)*8 + j.
// This makes proj's staging a linear lane-contiguous copy and the hot-loop
// ds_read_b128 the canonical m97 lane-linear pattern.
// ---------------------------------------------------------------------------
__global__ void wtrans_kernel(const float* __restrict__ Wk, const float* __restrict__ Wq,
                              const float* __restrict__ Wv, unsigned short* __restrict__ WTf) {
  int gid = blockIdx.x * 256 + threadIdx.x;
  if (gid >= 192 * CDIM) return;
  int n = gid / CDIM, kk = gid - n * CDIM;
  const float* W = (n < 64) ? Wq : (n < 128) ? Wk : Wv;
  int nt = n >> 4, ln = n & 15, ks = kk >> 5, sub = (kk >> 3) & 3, j = kk & 7;
  int lane = ln + 16 * sub;
  WTf[(((size_t)ks * 12 + nt) * 64 + lane) * 8 + j] =
      (unsigned short)f2bf(W[kk * HDIM + (n & 63)]);
}

// ---------------------------------------------------------------------------
// kernel 1: q,k,v = x @ [Wq|Wk|Wv].  512 blocks x 512 thr; block = 128 t-rows,
// wave = 16 rows.  WTf staged ONCE into LDS (147456 B, frag order, linear
// copy); x preloaded+packed to bx[12] (24 batched global loads per wave);
// hot loop = pure ds_read_b128 + MFMA, ks-outer/nt-inner so consecutive
// MFMAs hit independent accumulators.  No global latency in the loop
// (round-4 failure: compiler serialized/spilled global-fed MFMA batches).
// v exits via a 9 KB two-ping LDS transpose -> vT[B][H][T].
// ---------------------------------------------------------------------------
__global__ __launch_bounds__(512, 2) void proj_kernel(
    const float* __restrict__ x, const unsigned short* __restrict__ WTf,
    unsigned short* __restrict__ qws, unsigned short* __restrict__ kws,
    unsigned short* __restrict__ vT) {
  __shared__ unsigned short wtlds[73728];    // 147456 B, frag-order
  __shared__ unsigned short vtile[64][72];   // 9216 B    (total 156672 B)
  const int tid = threadIdx.x, bid = blockIdx.x;
  const int w = tid >> 6, lane = tid & 63;
  const int ln15 = lane & 15, quad = lane >> 4;

  // stage WTf -> LDS: linear 16-B chunks, 18 per thread
  {
    const uint4* src = (const uint4*)WTf;
    uint4* dst = (uint4*)wtlds;
    #pragma unroll
    for (int i = 0; i < 18; ++i) dst[i * 512 + tid] = src[i * 512 + tid];
  }

  // x preload + pack (overlaps staging; no LDS involved)
  const int t0 = bid * 128 + w * 16;
  const float* xrow = x + (size_t)(t0 + ln15) * CDIM + quad * 8;
  bf16x8 bx[12];
  #pragma unroll
  for (int hh = 0; hh < 2; ++hh) {
    float4 A[12];
    #pragma unroll
    for (int j = 0; j < 6; ++j) {
      A[2 * j]     = *(const float4*)(xrow + (hh * 6 + j) * 32);
      A[2 * j + 1] = *(const float4*)(xrow + (hh * 6 + j) * 32 + 4);
    }
    #pragma unroll
    for (int j = 0; j < 6; ++j) {
      bf16x8 t;
      t[0] = (short)f2bf(A[2 * j].x);     t[1] = (short)f2bf(A[2 * j].y);
      t[2] = (short)f2bf(A[2 * j].z);     t[3] = (short)f2bf(A[2 * j].w);
      t[4] = (short)f2bf(A[2 * j + 1].x); t[5] = (short)f2bf(A[2 * j + 1].y);
      t[6] = (short)f2bf(A[2 * j + 1].z); t[7] = (short)f2bf(A[2 * j + 1].w);
      bx[hh * 6 + j] = t;
    }
  }

  __syncthreads();

  f32x4 acc[12];
  #pragma unroll
  for (int nt = 0; nt < 12; ++nt) acc[nt] = (f32x4){0.f, 0.f, 0.f, 0.f};

  #pragma unroll
  for (int ks = 0; ks < 12; ++ks) {
    #pragma unroll
    for (int nt = 0; nt < 12; ++nt) {
      bf16x8 aw = *(const bf16x8*)&wtlds[((ks * 12 + nt) * 64 + lane) * 8];
      acc[nt] = __builtin_amdgcn_mfma_f32_16x16x32_bf16(aw, bx[ks], acc[nt], 0, 0, 0);
    }
  }

  // q/k epilogue: lane owns qkv[t0+ln15][nt*16 + quad*4 .. +3] -> packed 8B
  #pragma unroll
  for (int nt = 0; nt < 8; ++nt) {
    unsigned p0 = f2bf(acc[nt][0]) | (f2bf(acc[nt][1]) << 16);
    unsigned p1 = f2bf(acc[nt][2]) | (f2bf(acc[nt][3]) << 16);
    int hl = (nt & 3) * 16 + quad * 4;
    unsigned short* dst = (nt < 4) ? qws : kws;
    *(uint2*)&dst[(size_t)(t0 + ln15) * HDIM + hl] = (uint2){p0, p1};
  }

  // v two-ping transpose: ping p = waves 4p..4p+3 (local t 64p..64p+63)
  #pragma unroll
  for (int p = 0; p < 2; ++p) {
    if ((w >> 2) == p) {
      int tl = (w & 3) * 16 + ln15;
      #pragma unroll
      for (int nt = 8; nt < 12; ++nt) {
        int hl = (nt & 3) * 16 + quad * 4;
        #pragma unroll
        for (int i = 0; i < 4; ++i)
          vtile[hl + i][tl] = (unsigned short)f2bf(acc[nt][i]);
      }
    }
    __syncthreads();
    {
      int h = tid >> 3, c = tid & 7;
      uint4 d = *(const uint4*)&vtile[h][c * 8];
      *(uint4*)&vT[((size_t)(bid >> 1) * 64 + h) * SEQ + (bid & 1) * 128 + p * 64 + c * 8] = d;
    }
    __syncthreads();
  }
}

// ---------------------------------------------------------------------------
// kernel 2: causal attention (UNCHANGED from round 4 — kept identical so its
// counters surface in the next profile).  512 blocks x 512 thr; block (2b+h)
// does half of batch b's m-tiles, cost-balanced; LDS 79872 B.
// ---------------------------------------------------------------------------
__global__ __launch_bounds__(512, 4) void attn_kernel(
    const unsigned short* __restrict__ qws, const unsigned short* __restrict__ kws,
    const unsigned short* __restrict__ vT, float* __restrict__ out) {
  __shared__ unsigned short kl[256][72];     // 36864 B
  __shared__ unsigned short vt[64][264];     // 33792 B
  __shared__ unsigned short pl[8][16][36];   // 9216 B   (total 79872 B)
  const int tid = threadIdx.x;
  const int b = blockIdx.x >> 1, hgrp = blockIdx.x & 1;
  const int w = tid >> 6, lane = tid & 63;
  const int ln15 = lane & 15, quad = lane >> 4;

  for (int c = tid; c < 2048; c += 512) {    // k: 256x64 bf16
    int t = c >> 3, hc = c & 7;
    *(uint4*)&kl[t][hc * 8] = *(const uint4*)&kws[(size_t)(b * 256 + t) * HDIM + hc * 8];
  }
  for (int c = tid; c < 2048; c += 512) {    // vT[b]: 64x256 bf16, straight copy
    int hh = c >> 5, tc = c & 31;
    *(uint4*)&vt[hh][tc * 8] = *(const uint4*)&vT[(size_t)(b * 64 + hh) * SEQ + tc * 8];
  }
  __syncthreads();

  const int mt = 4 * (w >> 1) + (hgrp ? (1 + (w & 1)) : (3 * (w & 1)));
  const int t0 = mt * 16;
  const int NT = (mt | 1) + 1;               // even # of 16-wide s-tiles

  bf16x8 aq[2];
  #pragma unroll
  for (int ks = 0; ks < 2; ++ks)
    aq[ks] = *(const bf16x8*)&qws[(size_t)(b * 256 + t0 + ln15) * HDIM + ks * 32 + quad * 8];

  float sv[16][4];
  #pragma unroll
  for (int nt = 0; nt < 16; ++nt) {
    if (nt < NT) {
      f32x4 acc = (f32x4){0.f, 0.f, 0.f, 0.f};
      #pragma unroll
      for (int ks = 0; ks < 2; ++ks) {
        bf16x8 bf = *(const bf16x8*)&kl[nt * 16 + ln15][ks * 32 + quad * 8];
        acc = __builtin_amdgcn_mfma_f32_16x16x32_bf16(aq[ks], bf, acc, 0, 0, 0);
      }
      int colg = nt * 16 + ln15;
      #pragma unroll
      for (int i = 0; i < 4; ++i) {
        int rowg = t0 + quad * 4 + i;
        sv[nt][i] = (colg <= rowg) ? acc[i] * 0.125f : -3.0e38f;  // 1/sqrt(64)
      }
    }
  }
  float mx[4] = {-3.0e38f, -3.0e38f, -3.0e38f, -3.0e38f};
  #pragma unroll
  for (int nt = 0; nt < 16; ++nt)
    if (nt < NT) {
      #pragma unroll
      for (int i = 0; i < 4; ++i) mx[i] = fmaxf(mx[i], sv[nt][i]);
    }
  #pragma unroll
  for (int i = 0; i < 4; ++i) {              // reduce across the 16-lane group
    mx[i] = fmaxf(mx[i], __shfl_xor(mx[i], 8, 64));
    mx[i] = fmaxf(mx[i], __shfl_xor(mx[i], 4, 64));
    mx[i] = fmaxf(mx[i], __shfl_xor(mx[i], 2, 64));
    mx[i] = fmaxf(mx[i], __shfl_xor(mx[i], 1, 64));
  }
  float sm[4] = {0.f, 0.f, 0.f, 0.f};
  #pragma unroll
  for (int nt = 0; nt < 16; ++nt)
    if (nt < NT) {
      #pragma unroll
      for (int i = 0; i < 4; ++i) {
        float e = __expf(sv[nt][i] - mx[i]);
        sv[nt][i] = e;
        sm[i] += e;
      }
    }
  #pragma unroll
  for (int i = 0; i < 4; ++i) {
    sm[i] += __shfl_xor(sm[i], 8, 64);
    sm[i] += __shfl_xor(sm[i], 4, 64);
    sm[i] += __shfl_xor(sm[i], 2, 64);
    sm[i] += __shfl_xor(sm[i], 1, 64);
  }
  float inv[4];
  #pragma unroll
  for (int i = 0; i < 4; ++i) inv[i] = 1.0f / sm[i];

  // PV in 32-wide K chunks through the per-wave P buffer (wave-private; DS
  // pipe in-order so no barriers needed).
  f32x4 o[4];
  #pragma unroll
  for (int ont = 0; ont < 4; ++ont) o[ont] = (f32x4){0.f, 0.f, 0.f, 0.f};

  for (int kc = 0; kc < 8; ++kc) {
    if (kc * 2 < NT) {
      #pragma unroll
      for (int half = 0; half < 2; ++half) {
        int nt = kc * 2 + half;
        #pragma unroll
        for (int i = 0; i < 4; ++i)
          pl[w][quad * 4 + i][half * 16 + ln15] =
              (unsigned short)f2bf(sv[nt][i] * inv[i]);
      }
      bf16x8 pa = *(const bf16x8*)&pl[w][ln15][quad * 8];
      #pragma unroll
      for (int ont = 0; ont < 4; ++ont) {
        bf16x8 vb = *(const bf16x8*)&vt[ont * 16 + ln15][kc * 32 + quad * 8];
        o[ont] = __builtin_amdgcn_mfma_f32_16x16x32_bf16(pa, vb, o[ont], 0, 0, 0);
      }
    }
  }

  #pragma unroll
  for (int ont = 0; ont < 4; ++ont) {
    int h = ont * 16 + ln15;
    #pragma unroll
    for (int i = 0; i < 4; ++i)
      out[(size_t)(b * 256 + t0 + quad * 4 + i) * HDIM + h] = o[ont][i];
  }
}

// ---------------------------------------------------------------------------
// ws layout: WTf bf16 frag-order @0 (147456 B, pad to 256 KB), then q/k bf16
// row-major and vT bf16 [B][H][T] (8 MB each).  Needs ws_size >= 24.5 MB.
// ---------------------------------------------------------------------------
extern "C" void kernel_launch(void* const* d_in, const int* in_sizes, int n_in,
                              void* d_out, int out_size, void* d_ws, size_t ws_size,
                              hipStream_t stream) {
  const float* x  = (const float*)d_in[0];
  const float* Wk = (const float*)d_in[1];
  const float* Wq = (const float*)d_in[2];
  const float* Wv = (const float*)d_in[3];
  float* out = (float*)d_out;

  char* ws = (char*)d_ws;
  unsigned short* WTf = (unsigned short*)ws;
  unsigned short* qws = (unsigned short*)(ws + 262144);
  unsigned short* kws = qws + (size_t)BATCH * SEQ * HDIM;
  unsigned short* vT  = kws + (size_t)BATCH * SEQ * HDIM;

  wtrans_kernel<<<(192 * CDIM + 255) / 256, 256, 0, stream>>>(Wk, Wq, Wv, WTf);
  proj_kernel<<<512, 512, 0, stream>>>(x, WTf, qws, kws, vT);
  attn_kernel<<<2 * BATCH, 512, 0, stream>>>(qws, kws, vT, out);
}